// Round 14
// baseline (164.720 us; speedup 1.0000x reference)
//
#include <hip/hip_runtime.h>

// TopologyNetwork: B=1024, N=5000, K=16, 9 levels.
// R14 = R13's fused kernel, consuming idx/w RAW (k_pack deleted):
//  - edges are L2-resident either way; LDS pipe is the binder (measured
//    ~13 cyc per wave ds_read_b64: 8 base + 5 conflict, R10-R12 showed
//    scheduling recovers <=14% at net-negative cost). Unpacked edge stream
//    = 3.2 TB/s/XCD < L2 ceiling, fully overlapped -> packing buys nothing.
//  - one compute kernel: stage x (4 f16 cols/block) into LDS, 9 levels
//    ping-pong in 2x40000 B LDS, write out. Grid 256 = 1 block/CU, 16 waves.
//  - per node: 4x uint4 idx + 4x float4 w loads (64 B each, coalesced);
//    inline w->f16x2; gather ds_read_b64; packed f16x2 FMA.

#define TB 1024
#define TN 5000
#define TK 16
#define TLV 9
#define CPG 4                   // f16 cols per group (8 B per node-row)
#define NG  (TB / CPG)          // 256 col-groups = grid
#define LT  1024                // threads per block (16 waves)

typedef unsigned int u32;
typedef _Float16 h2 __attribute__((ext_vector_type(2)));

__device__ __forceinline__ h2 u2h(u32 v) { return __builtin_bit_cast(h2, v); }
__device__ __forceinline__ u32 h2u(h2 h) { return __builtin_bit_cast(u32, h); }
__device__ __forceinline__ u32 packf(float a, float b) {
    h2 h; h.x = (_Float16)a; h.y = (_Float16)b;
    return h2u(h);
}

// ---- fused: transpose-in + 9 levels in LDS + transpose-out ----
__global__ __launch_bounds__(LT) void k_fused(
    const float* __restrict__ x,      // [B,N]
    float* __restrict__ out,          // [B,N]
    const int* __restrict__ idx,      // [LV][TN][TK]
    const float* __restrict__ w,      // [LV][TN][TK]
    const float* __restrict__ biases) // [LV][TN]
{
    __shared__ uint2 buf[2][TN];      // 2 x 40000 B ping-pong
    const int g = blockIdx.x;
    const int t = threadIdx.x;

    // stage x cols g*4..g*4+3 as f16 rows
    {
        const float* xp0 = x + (size_t)(g * CPG + 0) * TN;
        const float* xp1 = x + (size_t)(g * CPG + 1) * TN;
        const float* xp2 = x + (size_t)(g * CPG + 2) * TN;
        const float* xp3 = x + (size_t)(g * CPG + 3) * TN;
        for (int n = t; n < TN; n += LT) {
            uint2 v;
            v.x = packf(xp0[n], xp1[n]);
            v.y = packf(xp2[n], xp3[n]);
            buf[0][n] = v;
        }
    }
    __syncthreads();

    int cur = 0;
    for (int l = 0; l < TLV; ++l) {
        const int*   idx_l = idx + (size_t)l * TN * TK;
        const float* w_l   = w   + (size_t)l * TN * TK;
        const float* b_l   = biases + (size_t)l * TN;
        for (int n = t; n < TN; n += LT) {
            // 16 edges of node n: idx 64 B + w 64 B, both contiguous
            const uint4*  ip = reinterpret_cast<const uint4*>(idx_l + (size_t)n * TK);
            const float4* wp = reinterpret_cast<const float4*>(w_l + (size_t)n * TK);
            const uint4  i0 = ip[0], i1 = ip[1], i2 = ip[2], i3 = ip[3];
            const float4 w0 = wp[0], w1 = wp[1], w2 = wp[2], w3 = wp[3];
            const u32   ss[TK] = {i0.x, i0.y, i0.z, i0.w,
                                  i1.x, i1.y, i1.z, i1.w,
                                  i2.x, i2.y, i2.z, i2.w,
                                  i3.x, i3.y, i3.z, i3.w};
            const float ws[TK] = {w0.x, w0.y, w0.z, w0.w,
                                  w1.x, w1.y, w1.z, w1.w,
                                  w2.x, w2.y, w2.z, w2.w,
                                  w3.x, w3.y, w3.z, w3.w};

            const float bvf = b_l[n];
            h2 bb; bb.x = (_Float16)bvf; bb.y = (_Float16)bvf;
            h2 a01 = bb, a23 = bb;

            #pragma unroll
            for (int k = 0; k < TK; ++k) {
                h2 wv; wv.x = (_Float16)ws[k]; wv.y = (_Float16)ws[k];
                const uint2 av = buf[cur][ss[k]];          // ds_read_b64
                a01 = wv * u2h(av.x) + a01;                // v_pk_fma_f16
                a23 = wv * u2h(av.y) + a23;
            }

            // LeakyReLU(0.1) = max(x, 0.1*x)
            h2 tenth; tenth.x = (_Float16)0.1f; tenth.y = (_Float16)0.1f;
            a01 = __builtin_elementwise_max(a01, a01 * tenth);
            a23 = __builtin_elementwise_max(a23, a23 * tenth);

            uint2 r; r.x = h2u(a01); r.y = h2u(a23);
            buf[cur ^ 1][n] = r;
        }
        __syncthreads();
        cur ^= 1;
    }

    // write out cols g*4..g*4+3
    {
        float* op0 = out + (size_t)(g * CPG + 0) * TN;
        float* op1 = out + (size_t)(g * CPG + 1) * TN;
        float* op2 = out + (size_t)(g * CPG + 2) * TN;
        float* op3 = out + (size_t)(g * CPG + 3) * TN;
        for (int n = t; n < TN; n += LT) {
            const uint2 v = buf[cur][n];
            h2 h;
            h = u2h(v.x); op0[n] = (float)h.x; op1[n] = (float)h.y;
            h = u2h(v.y); op2[n] = (float)h.x; op3[n] = (float)h.y;
        }
    }
}

extern "C" void kernel_launch(void* const* d_in, const int* in_sizes, int n_in,
                              void* d_out, int out_size, void* d_ws, size_t ws_size,
                              hipStream_t stream)
{
    const float* x       = (const float*)d_in[0];   // [B,N]
    const int*   src_idx = (const int*)  d_in[1];   // [LV,N,K]
    const float* weights = (const float*)d_in[2];   // [LV,N,K]
    const float* biases  = (const float*)d_in[3];   // [LV,N]
    float* out = (float*)d_out;                     // [B,N]

    (void)d_ws; (void)ws_size;

    // single fused 9-level evaluation
    hipLaunchKernelGGL(k_fused, dim3(NG), dim3(LT), 0, stream,
                       x, out, src_idx, weights, biases);
}